// Round 1
// baseline (3000.307 us; speedup 1.0000x reference)
//
#include <hip/hip_runtime.h>
#include <stdint.h>

#define S_ 1024
#define D_ 1024
#define H_ 16
#define DH_ 64
#define FF_ 4096
#define B_ 2
#define V_ 32000
#define CTX_ 1025
#define PAD_ 3

typedef unsigned short u16;
typedef __attribute__((ext_vector_type(8))) short bf16x8;
typedef __attribute__((ext_vector_type(4))) float f32x4;

enum { EPI_BF16 = 0, EPI_DUAL = 1, EPI_FC = 2, EPI_GELU_BF16 = 3, EPI_GELU_RES = 4, EPI_BIAS_F32 = 5 };

__device__ __forceinline__ u16 f2bf(float f) {
  unsigned u = __float_as_uint(f);
  return (u16)((u + 0x7FFFu + ((u >> 16) & 1u)) >> 16);
}

__device__ __forceinline__ float gelu_f(float x) {
  float t = tanhf(0.7978845608028654f * (x + 0.044715f * x * x * x));
  return 0.5f * x * (1.0f + t);
}

__device__ __forceinline__ void glds16(const void* g, void* l) {
  __builtin_amdgcn_global_load_lds(
      (const __attribute__((address_space(1))) unsigned int*)g,
      (__attribute__((address_space(3))) unsigned int*)l,
      16, 0, 0);
}

// ---------------- embedding gather ----------------
__global__ __launch_bounds__(256) void embed_gather(const int* __restrict__ text,
                                                    const float* __restrict__ emb,
                                                    float* __restrict__ x) {
  int row = blockIdx.x;             // 0..2047  (b*1024 + s)
  int b = row >> 10, s = row & 1023;
  int id = text[b * CTX_ + s];
  float4 v = ((const float4*)(emb + (size_t)id * D_))[threadIdx.x];
  ((float4*)(x + (size_t)row * D_))[threadIdx.x] = v;
}

// ---------------- relative positional encoding (bf16) ----------------
__global__ __launch_bounds__(256) void rel_enc(u16* __restrict__ rel) {
  int i = blockIdx.x;               // 0..1023
  float pos = (float)(S_ - 1 - i);
  for (int t = threadIdx.x; t < 512; t += 256) {
    float invf = exp2f(-(float)t * (13.287712379549449f / 512.0f)); // 10000^(-t/512)
    float ang = pos * invf;
    rel[(size_t)i * D_ + t] = f2bf(sinf(ang));
    rel[(size_t)i * D_ + 512 + t] = f2bf(cosf(ang));
  }
}

// ---------------- weight convert f32 (K,N) -> bf16 (N,K) ----------------
__global__ __launch_bounds__(256) void wconv_t(const float* __restrict__ src,
                                               u16* __restrict__ dst, int K, int N) {
  __shared__ float tile[32][33];
  int n0 = blockIdx.x * 32, k0 = blockIdx.y * 32;
  for (int idx = threadIdx.x; idx < 1024; idx += 256) {
    int r = idx >> 5, c = idx & 31;                 // r: k, c: n
    tile[r][c] = src[(size_t)(k0 + r) * N + n0 + c];
  }
  __syncthreads();
  for (int idx = threadIdx.x; idx < 1024; idx += 256) {
    int r = idx >> 5, c = idx & 31;                 // r: n, c: k
    dst[(size_t)(n0 + r) * K + k0 + c] = f2bf(tile[c][r]);
  }
}

// ---------------- layernorm (block per row) ----------------
__global__ __launch_bounds__(256) void layernorm_k(const float* __restrict__ x,
                                                   const float* __restrict__ g,
                                                   const float* __restrict__ bb,
                                                   float* __restrict__ outf,
                                                   u16* __restrict__ outb) {
  int row = blockIdx.x, tid = threadIdx.x;
  const float* xr = x + (size_t)row * D_;
  float4 v = ((const float4*)xr)[tid];
  float s = v.x + v.y + v.z + v.w;
  float s2 = v.x * v.x + v.y * v.y + v.z * v.z + v.w * v.w;
  __shared__ float red[8];
#pragma unroll
  for (int off = 32; off > 0; off >>= 1) { s += __shfl_xor(s, off); s2 += __shfl_xor(s2, off); }
  if ((tid & 63) == 0) { red[tid >> 6] = s; red[4 + (tid >> 6)] = s2; }
  __syncthreads();
  s = red[0] + red[1] + red[2] + red[3];
  s2 = red[4] + red[5] + red[6] + red[7];
  float mean = s * (1.0f / D_);
  float var = s2 * (1.0f / D_) - mean * mean;
  float rstd = rsqrtf(var + 1e-5f);
  float4 gv = ((const float4*)g)[tid];
  float4 bv = ((const float4*)bb)[tid];
  float y0 = (v.x - mean) * rstd * gv.x + bv.x;
  float y1 = (v.y - mean) * rstd * gv.y + bv.y;
  float y2 = (v.z - mean) * rstd * gv.z + bv.z;
  float y3 = (v.w - mean) * rstd * gv.w + bv.w;
  if (outf) ((float4*)(outf + (size_t)row * D_))[tid] = make_float4(y0, y1, y2, y3);
  ((ushort4*)(outb + (size_t)row * D_))[tid] = make_ushort4(f2bf(y0), f2bf(y1), f2bf(y2), f2bf(y3));
}

// ---------------- main GEMM: C(M,N) = A(M,K) @ Bt(N,K)^T ----------------
// 128x128 tile, BK=32, 4 waves (2x2), each wave 64x64 via 4x4 mfma_f32_16x16x32_bf16.
__global__ __launch_bounds__(256) void gemm_bt(const u16* __restrict__ A,
                                               const u16* __restrict__ Bt,
                                               int M, int N, int K,
                                               void* __restrict__ C0p, void* __restrict__ C1p,
                                               const float* __restrict__ bias0,
                                               const float* __restrict__ bias1,
                                               const float* __restrict__ res0,
                                               int ldc, int mode) {
  __shared__ u16 lA[128 * 32];
  __shared__ u16 lB[128 * 32];
  const int tid = threadIdx.x;
  const int wave = tid >> 6, lane = tid & 63;
  const int i0 = blockIdx.y * 128, j0 = blockIdx.x * 128;
  const int wm = wave & 1, wn = wave >> 1;
  const int m_lane = lane & 15, quad = lane >> 4;

  f32x4 acc[4][4] = {};

  const u16* Ab = A + (size_t)i0 * K;
  const u16* Bb = Bt + (size_t)j0 * K;
  const int r0 = wave * 32 + (lane >> 2);
  const int cb = (lane & 3) * 8;

  for (int k0 = 0; k0 < K; k0 += 32) {
    glds16(Ab + (size_t)r0 * K + k0 + cb, lA + wave * 1024);
    glds16(Ab + (size_t)(r0 + 16) * K + k0 + cb, lA + wave * 1024 + 512);
    glds16(Bb + (size_t)r0 * K + k0 + cb, lB + wave * 1024);
    glds16(Bb + (size_t)(r0 + 16) * K + k0 + cb, lB + wave * 1024 + 512);
    __syncthreads();
    bf16x8 af[4], bf[4];
#pragma unroll
    for (int t = 0; t < 4; t++) {
      af[t] = *(const bf16x8*)(lA + (wm * 64 + t * 16 + m_lane) * 32 + quad * 8);
      bf[t] = *(const bf16x8*)(lB + (wn * 64 + t * 16 + m_lane) * 32 + quad * 8);
    }
#pragma unroll
    for (int mt = 0; mt < 4; mt++)
#pragma unroll
      for (int nt = 0; nt < 4; nt++)
        acc[mt][nt] = __builtin_amdgcn_mfma_f32_16x16x32_bf16(af[mt], bf[nt], acc[mt][nt], 0, 0, 0);
    __syncthreads();
  }

#pragma unroll
  for (int mt = 0; mt < 4; mt++) {
#pragma unroll
    for (int nt = 0; nt < 4; nt++) {
      int col = j0 + wn * 64 + nt * 16 + m_lane;
      float b0 = bias0 ? bias0[col] : 0.0f;
#pragma unroll
      for (int r = 0; r < 4; r++) {
        int row = i0 + wm * 64 + mt * 16 + quad * 4 + r;
        size_t idx = (size_t)row * ldc + col;
        float v = acc[mt][nt][r];
        if (mode == EPI_BF16) {
          ((u16*)C0p)[idx] = f2bf(v);
        } else if (mode == EPI_DUAL) {
          ((u16*)C0p)[idx] = f2bf(v + b0);
          ((u16*)C1p)[idx] = f2bf(v + bias1[col]);
        } else if (mode == EPI_FC) {
          float* C0 = (float*)C0p;
          C0[idx] = C0[idx] + v + b0 + res0[idx];
        } else if (mode == EPI_GELU_BF16) {
          ((u16*)C0p)[idx] = f2bf(gelu_f(v + b0));
        } else if (mode == EPI_GELU_RES) {
          float* C0 = (float*)C0p;
          C0[idx] = C0[idx] + gelu_f(v + b0);
        } else { // EPI_BIAS_F32
          ((float*)C0p)[idx] = v + b0;
        }
      }
    }
  }
}

// ---------------- batched attention GEMM, 64x64 tile ----------------
// mode 0 (AC):  C[i,j]  = sum_d qu[i,d]*k[j,d]      (skip tj>ti)
// mode 1 (BD):  C[i, i+t-(S-1)] += sum_d qv[i,d]*r[t,d]   (skip ti+tj<15, j>=0 guard)
// mode 2 (AV):  o[i,d]  = sum_j aw[i,j]*vT[d,j]     (bf16 out)
__global__ __launch_bounds__(256) void attn_gemm(const u16* __restrict__ A, int lda,
                                                 const u16* __restrict__ Bt, int ldb,
                                                 float* __restrict__ Cf, u16* __restrict__ Cb,
                                                 int K, int mode) {
  const int ti = blockIdx.x, tj = blockIdx.y, bh = blockIdx.z;
  if (mode == 0 && tj > ti) return;
  if (mode == 1 && ti + tj < 15) return;
  const int b = bh >> 4, h = bh & 15;
  __shared__ u16 lA[64 * 64];
  __shared__ u16 lB[64 * 64];
  const int tid = threadIdx.x, wave = tid >> 6, lane = tid & 63;
  const int m_lane = lane & 15, quad = lane >> 4;
  const int i0 = ti * 64, j0 = tj * 64;

  size_t aoff, boff;
  if (mode == 0)      { aoff = (size_t)b * S_ * D_ + h * DH_; boff = (size_t)b * S_ * D_ + h * DH_; }
  else if (mode == 1) { aoff = (size_t)b * S_ * D_ + h * DH_; boff = (size_t)h * DH_; }
  else                { aoff = (size_t)bh * S_ * S_;          boff = (size_t)bh * DH_ * S_; }
  const u16* Ap = A + aoff + (size_t)i0 * lda;
  const u16* Bp = Bt + boff + (mode == 2 ? (size_t)0 : (size_t)j0 * ldb);

  f32x4 acc[4] = {};
  const int cid0 = wave * 128 + lane, cid1 = cid0 + 64;
  const int ar0 = cid0 >> 3, ac0 = (cid0 & 7) * 8;
  const int ar1 = cid1 >> 3, ac1 = (cid1 & 7) * 8;

  for (int k0 = 0; k0 < K; k0 += 64) {
    glds16(Ap + (size_t)ar0 * lda + k0 + ac0, lA + wave * 1024);
    glds16(Ap + (size_t)ar1 * lda + k0 + ac1, lA + wave * 1024 + 512);
    glds16(Bp + (size_t)ar0 * ldb + k0 + ac0, lB + wave * 1024);
    glds16(Bp + (size_t)ar1 * ldb + k0 + ac1, lB + wave * 1024 + 512);
    __syncthreads();
    bf16x8 a0 = *(const bf16x8*)(lA + (wave * 16 + m_lane) * 64 + quad * 8);
    bf16x8 a1 = *(const bf16x8*)(lA + (wave * 16 + m_lane) * 64 + 32 + quad * 8);
#pragma unroll
    for (int nt = 0; nt < 4; nt++) {
      bf16x8 b0 = *(const bf16x8*)(lB + (nt * 16 + m_lane) * 64 + quad * 8);
      bf16x8 b1 = *(const bf16x8*)(lB + (nt * 16 + m_lane) * 64 + 32 + quad * 8);
      acc[nt] = __builtin_amdgcn_mfma_f32_16x16x32_bf16(a0, b0, acc[nt], 0, 0, 0);
      acc[nt] = __builtin_amdgcn_mfma_f32_16x16x32_bf16(a1, b1, acc[nt], 0, 0, 0);
    }
    __syncthreads();
  }

  if (mode == 0) {
    float* C = Cf + (size_t)bh * S_ * S_;
#pragma unroll
    for (int nt = 0; nt < 4; nt++) {
      int col = j0 + nt * 16 + m_lane;
#pragma unroll
      for (int r = 0; r < 4; r++) {
        int row = i0 + wave * 16 + quad * 4 + r;
        C[(size_t)row * S_ + col] = acc[nt][r];
      }
    }
  } else if (mode == 1) {
    float* C = Cf + (size_t)bh * S_ * S_;
#pragma unroll
    for (int nt = 0; nt < 4; nt++) {
      int t = j0 + nt * 16 + m_lane;
#pragma unroll
      for (int r = 0; r < 4; r++) {
        int row = i0 + wave * 16 + quad * 4 + r;
        int j = row + t - (S_ - 1);
        if (j >= 0) C[(size_t)row * S_ + j] += acc[nt][r];
      }
    }
  } else {
    u16* C = Cb + (size_t)b * S_ * D_ + h * DH_;
#pragma unroll
    for (int nt = 0; nt < 4; nt++) {
      int col = nt * 16 + m_lane;  // d
#pragma unroll
      for (int r = 0; r < 4; r++) {
        int row = i0 + wave * 16 + quad * 4 + r;
        C[(size_t)row * D_ + col] = f2bf(acc[nt][r]);
      }
    }
  }
}

// ---------------- softmax over causal row (block per (i,bh)) ----------------
__global__ __launch_bounds__(256) void softmax_k(const float* __restrict__ scores,
                                                 u16* __restrict__ aw,
                                                 const int* __restrict__ text) {
  const int i = blockIdx.x, bh = blockIdx.y, b = bh >> 4;
  const float* s = scores + ((size_t)bh * S_ + i) * S_;
  u16* o = aw + ((size_t)bh * S_ + i) * S_;
  const int tid = threadIdx.x;
  if (text[b * CTX_ + i] == PAD_) {        // fully-masked query row -> aw = 0
    for (int j = tid; j < S_; j += 256) o[j] = 0;
    return;
  }
  __shared__ float red[8];
  const int n = i + 1;
  const float scale = 0.125f;              // 1/sqrt(64)
  float mx = -1e30f;
  for (int j = tid; j < n; j += 256) mx = fmaxf(mx, s[j]);
#pragma unroll
  for (int off = 32; off > 0; off >>= 1) mx = fmaxf(mx, __shfl_xor(mx, off));
  if ((tid & 63) == 0) red[tid >> 6] = mx;
  __syncthreads();
  mx = fmaxf(fmaxf(red[0], red[1]), fmaxf(red[2], red[3]));
  float mxs = mx * scale;
  float sum = 0.0f;
  for (int j = tid; j < n; j += 256) sum += __expf(s[j] * scale - mxs);
#pragma unroll
  for (int off = 32; off > 0; off >>= 1) sum += __shfl_xor(sum, off);
  __syncthreads();
  if ((tid & 63) == 0) red[4 + (tid >> 6)] = sum;
  __syncthreads();
  sum = red[4] + red[5] + red[6] + red[7];
  float inv = 1.0f / sum;
  for (int j = tid; j < S_; j += 256)
    o[j] = (j < n) ? f2bf(__expf(s[j] * scale - mxs) * inv) : (u16)0;
}

// ---------------- v transpose: (B*S, D) -> (B,H,DH,S) ----------------
__global__ __launch_bounds__(256) void v_transpose(const u16* __restrict__ v,
                                                   u16* __restrict__ vT) {
  int bh = blockIdx.y, b = bh >> 4, h = bh & 15;
  int j0 = blockIdx.x * 64;
  __shared__ u16 tile[64][65];
  for (int idx = threadIdx.x; idx < 4096; idx += 256) {
    int jj = idx >> 6, d = idx & 63;
    tile[jj][d] = v[(size_t)(b * S_ + j0 + jj) * D_ + h * DH_ + d];
  }
  __syncthreads();
  for (int idx = threadIdx.x; idx < 4096; idx += 256) {
    int d = idx >> 6, jj = idx & 63;
    vT[((size_t)bh * DH_ + d) * S_ + j0 + jj] = tile[jj][d];
  }
}

// =====================================================================
extern "C" void kernel_launch(void* const* d_in, const int* in_sizes, int n_in,
                              void* d_out, int out_size, void* d_ws, size_t ws_size,
                              hipStream_t stream) {
  (void)in_sizes; (void)n_in; (void)out_size;
  const int* text = (const int*)d_in[0];
  const float* emb = (const float*)d_in[1];
  const float* u_in = (const float*)d_in[2];
  const float* v_in = (const float*)d_in[3];
  const float* Wq = (const float*)d_in[4];
  const float* Wk = (const float*)d_in[5];
  const float* Wv = (const float*)d_in[6];
  const float* Wr = (const float*)d_in[7];
  const float* Wfc = (const float*)d_in[8];
  const float* bfc = (const float*)d_in[9];
  const float* ln1g = (const float*)d_in[10];
  const float* ln1b = (const float*)d_in[11];
  const float* ln2g = (const float*)d_in[12];
  const float* ln2b = (const float*)d_in[13];
  const float* W1 = (const float*)d_in[14];
  const float* b1 = (const float*)d_in[15];
  const float* W2 = (const float*)d_in[16];
  const float* b2 = (const float*)d_in[17];
  const float* lnfg = (const float*)d_in[18];
  const float* lnfb = (const float*)d_in[19];
  const float* Wlm = (const float*)d_in[20];
  const float* blm = (const float*)d_in[21];
  float* out = (float*)d_out;

  char* w = (char*)d_ws;
  size_t off = 0;
  auto alloc = [&](size_t bytes) -> void* {
    void* p = w + off;
    off += (bytes + 255) & ~(size_t)255;
    return p;
  };
  float* x    = (float*)alloc(2048ull * 1024 * 4);
  float* xnf  = (float*)alloc(2048ull * 1024 * 4);
  u16* xnb    = (u16*)alloc(2048ull * 1024 * 2);
  u16* relb   = (u16*)alloc(1024ull * 1024 * 2);
  u16* wqt    = (u16*)alloc(1024ull * 1024 * 2);
  u16* wkt    = (u16*)alloc(1024ull * 1024 * 2);
  u16* wvt    = (u16*)alloc(1024ull * 1024 * 2);
  u16* wrt    = (u16*)alloc(1024ull * 1024 * 2);
  u16* wfct   = (u16*)alloc(1024ull * 1024 * 2);
  u16* w1t    = (u16*)alloc(4096ull * 1024 * 2);
  u16* w2t    = (u16*)alloc(4096ull * 1024 * 2);
  u16* wlmt   = (u16*)alloc(32000ull * 1024 * 2);
  u16* qu     = (u16*)alloc(2048ull * 1024 * 2);
  u16* qv     = (u16*)alloc(2048ull * 1024 * 2);
  u16* kk     = (u16*)alloc(2048ull * 1024 * 2);
  u16* vv     = (u16*)alloc(2048ull * 1024 * 2);
  u16* vT     = (u16*)alloc(2048ull * 1024 * 2);
  u16* rb     = (u16*)alloc(1024ull * 1024 * 2);
  float* scores = (float*)alloc(32ull * 1024 * 1024 * 4);
  u16* aw     = (u16*)alloc(32ull * 1024 * 1024 * 2);
  u16* o_     = (u16*)alloc(2048ull * 1024 * 2);
  u16* f1     = (u16*)alloc(2048ull * 4096 * 2);
  if (off > ws_size) return;  // workspace too small; fail loudly via wrong output

  dim3 blk(256);
  embed_gather<<<2048, blk, 0, stream>>>(text, emb, x);
  rel_enc<<<1024, blk, 0, stream>>>(relb);
  wconv_t<<<dim3(1000, 32), blk, 0, stream>>>(Wlm, wlmt, 1024, 32000);

  for (int l = 0; l < 4; l++) {
    const size_t dd = 1048576;  // D*D
    wconv_t<<<dim3(32, 32), blk, 0, stream>>>(Wq + l * dd, wqt, 1024, 1024);
    wconv_t<<<dim3(32, 32), blk, 0, stream>>>(Wk + l * dd, wkt, 1024, 1024);
    wconv_t<<<dim3(32, 32), blk, 0, stream>>>(Wv + l * dd, wvt, 1024, 1024);
    wconv_t<<<dim3(32, 32), blk, 0, stream>>>(Wr + l * dd, wrt, 1024, 1024);
    wconv_t<<<dim3(32, 32), blk, 0, stream>>>(Wfc + l * dd, wfct, 1024, 1024);
    wconv_t<<<dim3(128, 32), blk, 0, stream>>>(W1 + l * 4ull * dd, w1t, 1024, 4096);
    wconv_t<<<dim3(32, 128), blk, 0, stream>>>(W2 + l * 4ull * dd, w2t, 4096, 1024);

    layernorm_k<<<2048, blk, 0, stream>>>(x, ln1g + l * 1024, ln1b + l * 1024, xnf, xnb);

    gemm_bt<<<dim3(8, 16), blk, 0, stream>>>(xnb, wqt, 2048, 1024, 1024, qu, qv, u_in, v_in, nullptr, 1024, EPI_DUAL);
    gemm_bt<<<dim3(8, 16), blk, 0, stream>>>(xnb, wkt, 2048, 1024, 1024, kk, nullptr, nullptr, nullptr, nullptr, 1024, EPI_BF16);
    gemm_bt<<<dim3(8, 16), blk, 0, stream>>>(xnb, wvt, 2048, 1024, 1024, vv, nullptr, nullptr, nullptr, nullptr, 1024, EPI_BF16);
    gemm_bt<<<dim3(8, 8), blk, 0, stream>>>(relb, wrt, 1024, 1024, 1024, rb, nullptr, nullptr, nullptr, nullptr, 1024, EPI_BF16);
    v_transpose<<<dim3(16, 32), blk, 0, stream>>>(vv, vT);

    attn_gemm<<<dim3(16, 16, 32), blk, 0, stream>>>(qu, 1024, kk, 1024, scores, nullptr, 64, 0);
    attn_gemm<<<dim3(16, 16, 32), blk, 0, stream>>>(qv, 1024, rb, 1024, scores, nullptr, 64, 1);
    softmax_k<<<dim3(1024, 32), blk, 0, stream>>>(scores, aw, text);
    attn_gemm<<<dim3(16, 1, 32), blk, 0, stream>>>(aw, 1024, vT, 1024, nullptr, o_, 1024, 2);

    gemm_bt<<<dim3(8, 16), blk, 0, stream>>>(o_, wfct, 2048, 1024, 1024, x, nullptr, bfc + l * 1024, nullptr, xnf, 1024, EPI_FC);
    layernorm_k<<<2048, blk, 0, stream>>>(x, ln2g + l * 1024, ln2b + l * 1024, nullptr, xnb);
    gemm_bt<<<dim3(32, 16), blk, 0, stream>>>(xnb, w1t, 2048, 4096, 1024, f1, nullptr, b1 + l * 4096, nullptr, nullptr, 4096, EPI_GELU_BF16);
    gemm_bt<<<dim3(8, 16), blk, 0, stream>>>(f1, w2t, 2048, 1024, 4096, x, nullptr, b2 + l * 1024, nullptr, nullptr, 1024, EPI_GELU_RES);
  }

  layernorm_k<<<2048, blk, 0, stream>>>(x, lnfg, lnfb, nullptr, xnb);
  gemm_bt<<<dim3(250, 16), blk, 0, stream>>>(xnb, wlmt, 2048, 32000, 1024, out, nullptr, blm, nullptr, nullptr, 32000, EPI_BIAS_F32);
}